// Round 13
// baseline (3464.661 us; speedup 1.0000x reference)
//
#include <hip/hip_runtime.h>
#include <hip/hip_bf16.h>
#include <cstdint>
#include <cstddef>

#define T_STEPS 8192
#define D_OBS 256
#define D_ACT 16
#define D_MLP 1024
#define D_REC 1024
#define G3REC 3072
#define TAIL_I 5          // wavefront iters 1..TAIL_I-1; sequential tail handles len > TAIL_I
#define K_MAX 16          // histogram cap for counting sort
#define HCAP 4608         // segment capacity (nseg ~ 4096 +/- 45; 11-sigma headroom)

typedef short bf16x8_t __attribute__((ext_vector_type(8)));
typedef float f32x4_t __attribute__((ext_vector_type(4)));

__device__ __forceinline__ float b2f(unsigned short u) {
  union { uint32_t i; float f; } v; v.i = ((uint32_t)u) << 16; return v.f;
}
__device__ __forceinline__ unsigned short f2b(float f) {
  union { float f; uint32_t i; } v; v.f = f;
  uint32_t r = v.i + 0x7fffu + ((v.i >> 16) & 1u);
  return (unsigned short)(r >> 16);
}
__device__ __forceinline__ float mishf(float v) {
  float sp = (v > 15.f) ? v : log1pf(expf(v));
  return v * tanhf(sp);
}
__device__ __forceinline__ float sigmf(float x) { return 1.f / (1.f + expf(-x)); }

// async global->LDS, 16B per lane; LDS dest = wave-uniform base + lane*16.
__device__ __forceinline__ void gload_lds16(const void* g, void* l) {
  __builtin_amdgcn_global_load_lds((const __attribute__((address_space(1))) void*)g,
                                   (__attribute__((address_space(3))) void*)l, 16, 0, 0);
}

// LDS swizzle (bank-conflict fix, both-sides rule #21), BK=32 tiles (r7: conflicts -> 0)
__device__ __forceinline__ int swz_src_j(int slot) {
  return (slot & 3) ^ ((slot >> 3) & 3);
}
__device__ __forceinline__ int swz_read_off(int row, int j) {
  return row * 32 + ((j ^ ((row >> 1) & 3)) << 3);
}

__device__ __forceinline__ int start_flag(const void* start, int mode, int t) {
  if (mode) return ((const unsigned char*)start)[t] != 0;
  return ((const int*)start)[t] != 0;
}

// ---- fused: start-dtype detect + segment build + counting sort (1 block) ----
__global__ __launch_bounds__(1024) void seg_all(
    const void* __restrict__ start,
    int* __restrict__ mode_p, int* __restrict__ nseg_p,
    int* __restrict__ t0s, int* __restrict__ len_s,
    int* __restrict__ counts) {
  __shared__ int st0[HCAP], slen[HCAP];
  __shared__ int hist[K_MAX + 2], off[K_MAX + 2];
  __shared__ int smode, snseg;
  int tid = threadIdx.x;
  if (tid == 0) {
    const unsigned int* w = (const unsigned int*)start;
    int m = 0;
    for (int i = 0; i < 64; ++i)
      if (w[i] > 1u) m = 1;   // int32 words of 0/1 bools are <=1; packed uint8 are not
    smode = m; snseg = 0; *mode_p = m;
  }
  if (tid < K_MAX + 2) hist[tid] = 0;
  __syncthreads();
  int mode = smode;
  for (int t = tid; t < T_STEPS; t += 1024) {
    if (t != 0 && !start_flag(start, mode, t)) continue;
    int len = 1;
    while (t + len < T_STEPS && !start_flag(start, mode, t + len)) ++len;
    int slot = atomicAdd(&snseg, 1);
    if (slot < HCAP) {
      st0[slot] = t; slen[slot] = len;
      atomicAdd(&hist[min(len, K_MAX + 1)], 1);
    }
  }
  __syncthreads();
  if (tid == 0) {
    *nseg_p = min(snseg, HCAP);
    int acc = 0;
    for (int b = K_MAX + 1; b >= 1; --b) { off[b] = acc; acc += hist[b]; }
    for (int i = 0; i <= K_MAX; ++i) {
      int c = 0;
      for (int b = i + 1; b <= K_MAX + 1; ++b) c += hist[b];
      counts[i] = c;
    }
  }
  __syncthreads();
  int n = min(snseg, HCAP);
  for (int s = tid; s < n; s += 1024) {
    int pos = atomicAdd(&off[min(slen[s], K_MAX + 1)], 1);
    t0s[pos] = st0[s]; len_s[pos] = slen[s];
  }
}

// ---- all f32->bf16 conversions in one kernel (5 jobs by index range) ----
__global__ __launch_bounds__(256) void cvt_all(
    const float* __restrict__ x, const float* __restrict__ wpre,
    const float* __restrict__ wih, const float* __restrict__ w1,
    const float* __restrict__ w2,
    unsigned short* __restrict__ ox, unsigned short* __restrict__ owpre,
    unsigned short* __restrict__ owih, unsigned short* __restrict__ ow1,
    unsigned short* __restrict__ ow2) {
  int stride = gridDim.x * blockDim.x;
  for (int jq = blockIdx.x * blockDim.x + threadIdx.x; jq < 1900544; jq += stride) {
    const float* in; unsigned short* out; int o;
    if (jq < 524288)       { in = x;    out = ox;    o = jq; }
    else if (jq < 589824)  { in = wpre; out = owpre; o = jq - 524288; }
    else if (jq < 1376256) { in = wih;  out = owih;  o = jq - 589824; }
    else if (jq < 1638400) { in = w1;   out = ow1;   o = jq - 1376256; }
    else                   { in = w2;   out = ow2;   o = jq - 1638400; }
    float4 v = ((const float4*)in)[o];
    ushort4 r;
    r.x = f2b(v.x); r.y = f2b(v.y); r.z = f2b(v.z); r.w = f2b(v.w);
    ((ushort4*)out)[o] = r;
  }
}

// w_hh [3072,1024] f32 -> w_perm bf16 with row permutation: out row 3u+g = in row g*1024+u.
__global__ __launch_bounds__(256) void cvt_whh_perm(
    const float* __restrict__ in, unsigned short* __restrict__ out) {
  int r = blockIdx.x;
  int g = r >> 10, u = r & 1023;
  unsigned short* dst = out + (size_t)(u * 3 + g) * D_REC;
  const float* src = in + (size_t)r * D_REC;
  for (int c = threadIdx.x * 4; c < D_REC; c += 1024) {
    float4 v = *(const float4*)&src[c];
    ushort4 o; o.x = f2b(v.x); o.y = f2b(v.y); o.z = f2b(v.z); o.w = f2b(v.w);
    *(ushort4*)&dst[c] = o;
  }
}

// C[M,N] = act(A[M,K] @ B[N,K]^T + bias[N]); bf16 in/out, f32 accum.
// dbuf global_load_lds staging + swizzled LDS (conflict-free, r7-proven).
// No XCD swizzle: r12 A/B showed it trebles FETCH_SIZE here (L3 temporal
// locality of the natural dispatch order beats per-XCD chunking).
template <int ACT, int MT, int NT>
__global__ __launch_bounds__(256) void gemm_tn(
    const unsigned short* __restrict__ A,
    const unsigned short* __restrict__ B,
    const float* __restrict__ bias,
    unsigned short* __restrict__ C,
    int M, int N, int K) {
  constexpr int BM = MT * 32, BN = NT * 32;
  constexpr int CA = BM / 64, CB = BN / 64;
  __shared__ unsigned short lds_a[2][BM * 32];
  __shared__ unsigned short lds_b[2][BN * 32];
  const int tid = threadIdx.x;
  const int lane = tid & 63;
  const int wave = tid >> 6;
  const int wr = wave >> 1, wc = wave & 1;
  const int row0 = blockIdx.x * BM, col0 = blockIdx.y * BN;
  f32x4_t acc[MT][NT] = {};
  const int lrow = lane & 15, j = lane >> 4;
  const unsigned short* srcA[CA];
  const unsigned short* srcB[CB];
#pragma unroll
  for (int p = 0; p < CA; ++p) {
    int slot = p * 256 + tid;
    srcA[p] = &A[(size_t)(row0 + (slot >> 2)) * K + swz_src_j(slot) * 8];
  }
#pragma unroll
  for (int p = 0; p < CB; ++p) {
    int slot = p * 256 + tid;
    srcB[p] = &B[(size_t)(col0 + (slot >> 2)) * K + swz_src_j(slot) * 8];
  }
  const int so = wave * 512;
  auto stage = [&](int buf, int k0) {
#pragma unroll
    for (int p = 0; p < CA; ++p)
      gload_lds16(srcA[p] + k0, &lds_a[buf][p * 2048 + so]);
#pragma unroll
    for (int p = 0; p < CB; ++p)
      gload_lds16(srcB[p] + k0, &lds_b[buf][p * 2048 + so]);
  };
  int aoff[MT], boff[NT];
#pragma unroll
  for (int m = 0; m < MT; ++m)
    aoff[m] = swz_read_off(wr * (MT * 16) + m * 16 + lrow, j);
#pragma unroll
  for (int n = 0; n < NT; ++n)
    boff[n] = swz_read_off(wc * (NT * 16) + n * 16 + lrow, j);
  const int nk = K >> 5;
  stage(0, 0);
  __syncthreads();
  int cur = 0;
  for (int t = 0; t < nk; ++t) {
    if (t + 1 < nk) stage(cur ^ 1, (t + 1) << 5);
    bf16x8_t af[MT], bfr[NT];
#pragma unroll
    for (int m = 0; m < MT; ++m)
      af[m] = *(const bf16x8_t*)&lds_a[cur][aoff[m]];
#pragma unroll
    for (int n = 0; n < NT; ++n)
      bfr[n] = *(const bf16x8_t*)&lds_b[cur][boff[n]];
#pragma unroll
    for (int m = 0; m < MT; ++m)
#pragma unroll
      for (int n = 0; n < NT; ++n)
        acc[m][n] = __builtin_amdgcn_mfma_f32_16x16x32_bf16(af[m], bfr[n], acc[m][n], 0, 0, 0);
    __syncthreads();
    cur ^= 1;
  }
#pragma unroll
  for (int n = 0; n < NT; ++n) {
    int col = col0 + wc * (NT * 16) + n * 16 + lrow;
    float bv = bias[col];
#pragma unroll
    for (int m = 0; m < MT; ++m) {
#pragma unroll
      for (int jj = 0; jj < 4; ++jj) {
        int row = row0 + wr * (MT * 16) + m * 16 + j * 4 + jj;
        float v = acc[m][n][jj] + bv;
        if (ACT) v = mishf(v);
        C[(size_t)row * N + col] = f2b(v);
      }
    }
  }
}

// ---- hg0 = w_hh(f32) @ state0(f32) ----
__global__ __launch_bounds__(256) void matvec0(
    const float* __restrict__ w_hh, const float* __restrict__ state0,
    float* __restrict__ hg0) {
  int g = threadIdx.x >> 4, l16 = threadIdx.x & 15;
  int row = blockIdx.x * 16 + g;
  const float* wr = w_hh + (size_t)row * D_REC;
  float s = 0.f;
#pragma unroll
  for (int i = 0; i < 16; ++i) {
    int c = (l16 + i * 16) * 4;
    float4 w4 = *(const float4*)&wr[c];
    float4 h4 = *(const float4*)&state0[c];
    s += w4.x * h4.x + w4.y * h4.y + w4.z * h4.z + w4.w * h4.w;
  }
#pragma unroll
  for (int o = 1; o < 16; o <<= 1) s += __shfl_xor(s, o);
  if (l16 == 0) hg0[row] = s;
}

// ---- iteration 0 gate ----
__global__ __launch_bounds__(256) void gru_gate0(
    unsigned short* __restrict__ states, const unsigned short* __restrict__ igates,
    const void* __restrict__ start, const int* __restrict__ mode_p,
    const int* __restrict__ t0s, const int* __restrict__ nseg_p,
    const float* __restrict__ hg0, const float* __restrict__ state0,
    const float* __restrict__ b_n, float* __restrict__ Hf32,
    float* __restrict__ finals) {
  int p = blockIdx.x;
  if (p >= *nseg_p) return;
  int t0 = t0s[p];
  int mode = *mode_p;
  bool use_s0 = (t0 == 0) && !start_flag(start, mode, 0);
  size_t ib = (size_t)t0 * G3REC;
  for (int u = threadIdx.x; u < D_REC; u += 256) {
    float hp = use_s0 ? state0[u] : 0.f;
    float hr = use_s0 ? hg0[u] : 0.f;
    float hz = use_s0 ? hg0[D_REC + u] : 0.f;
    float hn = use_s0 ? hg0[2 * D_REC + u] : 0.f;
    float r = sigmf(b2f(igates[ib + u]) + hr);
    float z = sigmf(b2f(igates[ib + D_REC + u]) + hz);
    float n = tanhf(b2f(igates[ib + 2 * D_REC + u]) + r * (hn + b_n[u]));
    float hnew = n + z * (hp - n);
    Hf32[(size_t)p * D_REC + u] = hnew;
    states[(size_t)t0 * D_REC + u] = f2b(hnew);
    if (t0 == T_STEPS - 1) finals[u] = hnew;
  }
}

// ---- fused wavefront iteration i in 1..TAIL_I-1: 64 segs x 96 w_perm rows.
// r10-proven config: 25KB LDS, ~6 blocks/CU (HBM-latency-bound gather -> TLP).
__global__ __launch_bounds__(256) void gru_iter(
    unsigned short* __restrict__ states,
    const unsigned short* __restrict__ igates,
    const unsigned short* __restrict__ w_perm,
    const int* __restrict__ t0s, const int* __restrict__ counts,
    const float* __restrict__ b_n, float* __restrict__ Hf32,
    float* __restrict__ finals, int iter) {
  const int count = counts[iter];
  const int row0 = blockIdx.x * 64;
  if (row0 >= count) return;
  const int u0 = blockIdx.y * 32;
  const int col0 = u0 * 3;
  __shared__ __align__(16) float smem_f[64 * 98];   // 25088 B
  unsigned short* sb = (unsigned short*)smem_f;
  float* hgl = smem_f;                              // [64][98] f32 after K-loop
  const int tid = threadIdx.x;
  const int lane = tid & 63, wave = tid >> 6;
  const int lrow = lane & 15, j = lane >> 4;
  const int rA = tid >> 2;
  const int c8sw = swz_src_j(tid) * 8;
  int gA = (row0 + rA < count) ? (t0s[row0 + rA] + iter - 1) : (t0s[0] + iter - 1);
  const unsigned short* srcA  = states + (size_t)gA * D_REC + c8sw;
  const unsigned short* srcB0 = w_perm + (size_t)(col0 + rA) * D_REC + c8sw;
  const unsigned short* srcB1 = w_perm + (size_t)(col0 + 64 + rA) * D_REC + c8sw; // tid<128
  const int soA = wave * 512;
  auto stage = [&](int buf, int k0) {
    gload_lds16(srcA + k0, sb + buf * 2048 + soA);
    gload_lds16(srcB0 + k0, sb + 4096 + buf * 3072 + soA);
    if (tid < 128)
      gload_lds16(srcB1 + k0, sb + 4096 + buf * 3072 + 2048 + soA);
  };
  f32x4_t acc[6] = {};
  const int aoff = swz_read_off(wave * 16 + lrow, j);
  int boff[6];
#pragma unroll
  for (int n = 0; n < 6; ++n)
    boff[n] = swz_read_off(n * 16 + lrow, j);
  stage(0, 0);
  __syncthreads();
  int cur = 0;
  for (int t = 0; t < 32; ++t) {
    if (t + 1 < 32) stage(cur ^ 1, (t + 1) << 5);
    const unsigned short* ca = sb + cur * 2048;
    const unsigned short* cb = sb + 4096 + cur * 3072;
    bf16x8_t af = *(const bf16x8_t*)&ca[aoff];
    bf16x8_t bfr[6];
#pragma unroll
    for (int n = 0; n < 6; ++n)
      bfr[n] = *(const bf16x8_t*)&cb[boff[n]];
#pragma unroll
    for (int n = 0; n < 6; ++n)
      acc[n] = __builtin_amdgcn_mfma_f32_16x16x32_bf16(af, bfr[n], acc[n], 0, 0, 0);
    __syncthreads();
    cur ^= 1;
  }
#pragma unroll
  for (int n = 0; n < 6; ++n)
#pragma unroll
    for (int jj = 0; jj < 4; ++jj) {
      int row = wave * 16 + j * 4 + jj;
      hgl[row * 98 + n * 16 + lrow] = acc[n][jj];
    }
  __syncthreads();
#pragma unroll
  for (int k = 0; k < 8; ++k) {
    int idx = k * 256 + tid;
    int pl = idx >> 5, ul = idx & 31;
    int p = row0 + pl;
    if (p >= count) continue;
    int t = t0s[p] + iter;
    int u = u0 + ul;
    float hr = hgl[pl * 98 + 3 * ul + 0];
    float hz = hgl[pl * 98 + 3 * ul + 1];
    float hn = hgl[pl * 98 + 3 * ul + 2];
    size_t ib = (size_t)t * G3REC;
    float hp = Hf32[(size_t)p * D_REC + u];
    float r = sigmf(b2f(igates[ib + u]) + hr);
    float z = sigmf(b2f(igates[ib + D_REC + u]) + hz);
    float n = tanhf(b2f(igates[ib + 2 * D_REC + u]) + r * (hn + b_n[u]));
    float hnew = n + z * (hp - n);
    Hf32[(size_t)p * D_REC + u] = hnew;
    states[(size_t)t * D_REC + u] = f2b(hnew);
    if (t == T_STEPS - 1) finals[u] = hnew;
  }
}

// ---- sequential tail: one block per segment with len > TAIL_I, runs steps
// TAIL_I..len-1 (cleanup-style matvec; same structure as r2's validated scan).
// Replaces 11 near-empty wavefront launches (counts[5] ~ 128 segs, avg ~1.3
// extra steps) — no cross-block dependency, so no grid sync needed.
__global__ __launch_bounds__(256) void gru_tail(
    unsigned short* __restrict__ states, const unsigned short* __restrict__ igates,
    const unsigned short* __restrict__ w_perm,
    const int* __restrict__ t0s, const int* __restrict__ len_s,
    const int* __restrict__ counts, const float* __restrict__ b_n,
    const float* __restrict__ Hf32, float* __restrict__ finals) {
  int p = blockIdx.x;
  if (p >= counts[TAIL_I]) return;  // sorted-first prefix: len > TAIL_I
  int t0 = t0s[p], len = len_s[p];
  __shared__ float h[D_REC];
  __shared__ float hgl[G3REC];
  const int tid = threadIdx.x;
  for (int u = tid; u < D_REC; u += 256) h[u] = Hf32[(size_t)p * D_REC + u];
  __syncthreads();
  const int g = tid >> 4, l16 = tid & 15;
  for (int s = TAIL_I; s < len; ++s) {
    int t = t0 + s;
    float hreg[64];
#pragma unroll
    for (int i = 0; i < 8; ++i) {
      float4 a = *(const float4*)&h[l16 * 8 + i * 128];
      float4 b = *(const float4*)&h[l16 * 8 + i * 128 + 4];
      hreg[i * 8 + 0] = a.x; hreg[i * 8 + 1] = a.y; hreg[i * 8 + 2] = a.z; hreg[i * 8 + 3] = a.w;
      hreg[i * 8 + 4] = b.x; hreg[i * 8 + 5] = b.y; hreg[i * 8 + 6] = b.z; hreg[i * 8 + 7] = b.w;
    }
    for (int row = g; row < G3REC; row += 16) {
      const unsigned short* wrow = w_perm + (size_t)row * D_REC;
      float sum = 0.f;
#pragma unroll
      for (int i = 0; i < 8; ++i) {
        bf16x8_t wv = *(const bf16x8_t*)&wrow[l16 * 8 + i * 128];
#pragma unroll
        for (int jj = 0; jj < 8; ++jj)
          sum += b2f((unsigned short)wv[jj]) * hreg[i * 8 + jj];
      }
#pragma unroll
      for (int o = 1; o < 16; o <<= 1) sum += __shfl_xor(sum, o);
      if (l16 == 0) hgl[row] = sum;
    }
    __syncthreads();
    size_t ib = (size_t)t * G3REC;
    for (int u = tid; u < D_REC; u += 256) {
      float r = sigmf(b2f(igates[ib + u]) + hgl[3 * u + 0]);
      float z = sigmf(b2f(igates[ib + D_REC + u]) + hgl[3 * u + 1]);
      float n = tanhf(b2f(igates[ib + 2 * D_REC + u]) + r * (hgl[3 * u + 2] + b_n[u]));
      float hnew = n + z * (h[u] - n);
      h[u] = hnew;
      states[(size_t)t * D_REC + u] = f2b(hnew);
      if (t == T_STEPS - 1) finals[u] = hnew;
    }
    __syncthreads();
  }
}

// ---- heads + dueling epilogue: one wave per 4 rows (weight loads amortized 4x) ----
__global__ __launch_bounds__(64) void heads_kernel(
    const unsigned short* __restrict__ y,
    const float* __restrict__ Wv, const float* __restrict__ bv,
    const float* __restrict__ Wa, const float* __restrict__ ba,
    const float* __restrict__ Ws, const float* __restrict__ bs,
    float* __restrict__ q) {
  const int t0 = blockIdx.x * 4, lane = threadIdx.x;
  float yv[4][16];
#pragma unroll
  for (int s = 0; s < 4; ++s) {
    const unsigned short* yr = y + (size_t)(t0 + s) * D_MLP;
#pragma unroll
    for (int c = 0; c < 2; ++c) {
      bf16x8_t v = *(const bf16x8_t*)&yr[lane * 16 + c * 8];
#pragma unroll
      for (int jj = 0; jj < 8; ++jj) yv[s][c * 8 + jj] = b2f((unsigned short)v[jj]);
    }
  }
  float mine[4] = {};
  for (int o = 0; o < 18; ++o) {
    const float* w = (o < 16) ? (Wa + (size_t)o * D_MLP) : (o == 16 ? Wv : Ws);
    float4 wv[4];
#pragma unroll
    for (int c = 0; c < 4; ++c) wv[c] = *(const float4*)&w[lane * 16 + c * 4];
#pragma unroll
    for (int s = 0; s < 4; ++s) {
      float ss = 0.f;
#pragma unroll
      for (int c = 0; c < 4; ++c)
        ss += wv[c].x * yv[s][c * 4 + 0] + wv[c].y * yv[s][c * 4 + 1] +
              wv[c].z * yv[s][c * 4 + 2] + wv[c].w * yv[s][c * 4 + 3];
#pragma unroll
      for (int off = 1; off < 64; off <<= 1) ss += __shfl_xor(ss, off);
      if (lane == o) mine[s] = ss;
    }
  }
#pragma unroll
  for (int s = 0; s < 4; ++s) {
    float m = mine[s];
    if (lane < 16) m += ba[lane];
    else if (lane == 16) m += bv[0];
    else if (lane == 17) m += bs[0];
    float a = (lane < 16) ? m : 0.f;
    float ss = a * a;
#pragma unroll
    for (int off = 1; off < 64; off <<= 1) ss += __shfl_xor(ss, off);
    float an = a / (1e-6f + sqrtf(ss));
    float ms = (lane < 16) ? an : 0.f;
#pragma unroll
    for (int off = 1; off < 64; off <<= 1) ms += __shfl_xor(ms, off);
    float adv = an - ms * (1.f / 16.f);
    float val = __shfl(m, 16);
    float sc = __shfl(m, 17);
    if (lane < 16) q[(size_t)(t0 + s) * D_ACT + lane] = val + sc * adv;
  }
}

extern "C" void kernel_launch(void* const* d_in, const int* in_sizes, int n_in,
                              void* d_out, int out_size, void* d_ws, size_t ws_size,
                              hipStream_t stream) {
  const float* x      = (const float*)d_in[0];
  const float* state0 = (const float*)d_in[1];
  const void*  start  = d_in[2];
  const float* W_pre  = (const float*)d_in[3];
  const float* b_pre  = (const float*)d_in[4];
  const float* w_ih   = (const float*)d_in[5];
  const float* w_hh   = (const float*)d_in[6];
  const float* b_ih   = (const float*)d_in[7];
  const float* b_n    = (const float*)d_in[8];
  const float* W1     = (const float*)d_in[9];
  const float* b1     = (const float*)d_in[10];
  const float* W2     = (const float*)d_in[11];
  const float* b2     = (const float*)d_in[12];
  const float* Wv     = (const float*)d_in[13];
  const float* bv     = (const float*)d_in[14];
  const float* Wa     = (const float*)d_in[15];
  const float* ba     = (const float*)d_in[16];
  const float* Ws     = (const float*)d_in[17];
  const float* bs     = (const float*)d_in[18];

  char* ws = (char*)d_ws;
  const size_t MB = 1ull << 20;
  unsigned short* igates = (unsigned short*)(ws);
  unsigned short* y2     = igates;
  unsigned short* xp     = (unsigned short*)(ws + 48 * MB);
  float*          Hf32   = (float*)(ws + 48 * MB);
  unsigned short* y1     = xp;
  unsigned short* states = (unsigned short*)(ws + 66 * MB);
  unsigned short* x_bf   = (unsigned short*)(ws + 82 * MB);
  unsigned short* w_perm = (unsigned short*)(ws + 82 * MB);
  unsigned short* Wpre_bf= (unsigned short*)(ws + 88 * MB);
  unsigned short* wih_bf = (unsigned short*)(ws + 88 * MB + 512 * 1024);
  unsigned short* W1_bf  = (unsigned short*)(ws + 94 * MB + 512 * 1024);
  unsigned short* W2_bf  = (unsigned short*)(ws + 96 * MB + 512 * 1024);
  char* seg = ws + 98 * MB + 512 * 1024;
  int* t0s     = (int*)(seg);
  int* len_s   = (int*)(seg + 32768);
  int* counts  = (int*)(seg + 65536);
  int* nseg_p  = (int*)(seg + 65536 + 128);
  int* mode_p  = (int*)(seg + 65536 + 192);
  float* hg0   = (float*)(seg + 65536 + 512);
  float* qout   = (float*)d_out;
  float* finals = qout + (size_t)T_STEPS * D_ACT;

  seg_all<<<1, 1024, 0, stream>>>(start, mode_p, nseg_p, t0s, len_s, counts);
  cvt_all<<<2048, 256, 0, stream>>>(x, W_pre, w_ih, W1, W2,
                                    x_bf, Wpre_bf, wih_bf, W1_bf, W2_bf);
  matvec0<<<192, 256, 0, stream>>>(w_hh, state0, hg0);

  gemm_tn<1, 2, 2><<<dim3(128, 16), 256, 0, stream>>>(x_bf, Wpre_bf, b_pre, xp, T_STEPS, D_MLP, D_OBS);
  cvt_whh_perm<<<3072, 256, 0, stream>>>(w_hh, w_perm);
  gemm_tn<0, 4, 4><<<dim3(64, 24), 256, 0, stream>>>(xp, wih_bf, b_ih, igates, T_STEPS, G3REC, D_MLP);

  gru_gate0<<<HCAP, 256, 0, stream>>>(states, igates, start, mode_p, t0s, nseg_p,
                                      hg0, state0, b_n, Hf32, finals);
  for (int i = 1; i < TAIL_I; ++i) {
    int mt = (8192 / (i + 1) + 63) / 64;  // count_i <= 8192/(i+1)
    gru_iter<<<dim3(mt, 32), 256, 0, stream>>>(states, igates, w_perm, t0s, counts,
                                               b_n, Hf32, finals, i);
  }
  gru_tail<<<1024, 256, 0, stream>>>(states, igates, w_perm, t0s, len_s, counts,
                                     b_n, Hf32, finals);

  gemm_tn<1, 2, 2><<<dim3(128, 16), 256, 0, stream>>>(states, W1_bf, b1, y1, T_STEPS, D_MLP, D_REC);
  gemm_tn<1, 2, 2><<<dim3(128, 16), 256, 0, stream>>>(y1, W2_bf, b2, y2, T_STEPS, D_MLP, D_MLP);
  heads_kernel<<<2048, 64, 0, stream>>>(y2, Wv, bv, Wa, ba, Ws, bs, qout);
}

// Round 14
// 495.366 us; speedup vs baseline: 6.9941x; 6.9941x over previous
//
#include <hip/hip_runtime.h>
#include <hip/hip_bf16.h>
#include <cstdint>
#include <cstddef>

#define T_STEPS 8192
#define D_OBS 256
#define D_ACT 16
#define D_MLP 1024
#define D_REC 1024
#define G3REC 3072
#define K_MAX 16          // wavefront iters 1..15; cleanup handles len > 16
#define HCAP 4608         // segment capacity (nseg ~ 4096 +/- 45; 11-sigma headroom)

typedef short bf16x8_t __attribute__((ext_vector_type(8)));
typedef float f32x4_t __attribute__((ext_vector_type(4)));

__device__ __forceinline__ float b2f(unsigned short u) {
  union { uint32_t i; float f; } v; v.i = ((uint32_t)u) << 16; return v.f;
}
__device__ __forceinline__ unsigned short f2b(float f) {
  union { float f; uint32_t i; } v; v.f = f;
  uint32_t r = v.i + 0x7fffu + ((v.i >> 16) & 1u);
  return (unsigned short)(r >> 16);
}
__device__ __forceinline__ float mishf(float v) {
  float sp = (v > 15.f) ? v : log1pf(expf(v));
  return v * tanhf(sp);
}
__device__ __forceinline__ float sigmf(float x) { return 1.f / (1.f + expf(-x)); }

// async global->LDS, 16B per lane; LDS dest = wave-uniform base + lane*16.
__device__ __forceinline__ void gload_lds16(const void* g, void* l) {
  __builtin_amdgcn_global_load_lds((const __attribute__((address_space(1))) void*)g,
                                   (__attribute__((address_space(3))) void*)l, 16, 0, 0);
}

// LDS swizzle (bank-conflict fix, both-sides rule #21), BK=32 tiles (r7: conflicts -> 0)
__device__ __forceinline__ int swz_src_j(int slot) {
  return (slot & 3) ^ ((slot >> 3) & 3);
}
__device__ __forceinline__ int swz_read_off(int row, int j) {
  return row * 32 + ((j ^ ((row >> 1) & 3)) << 3);
}

__device__ __forceinline__ int start_flag(const void* start, int mode, int t) {
  if (mode) return ((const unsigned char*)start)[t] != 0;
  return ((const int*)start)[t] != 0;
}

// ---- fused: start-dtype detect + segment build + counting sort (1 block) ----
__global__ __launch_bounds__(1024) void seg_all(
    const void* __restrict__ start,
    int* __restrict__ mode_p, int* __restrict__ nseg_p,
    int* __restrict__ t0s, int* __restrict__ len_s,
    int* __restrict__ counts) {
  __shared__ int st0[HCAP], slen[HCAP];
  __shared__ int hist[K_MAX + 2], off[K_MAX + 2];
  __shared__ int smode, snseg;
  int tid = threadIdx.x;
  if (tid == 0) {
    const unsigned int* w = (const unsigned int*)start;
    int m = 0;
    for (int i = 0; i < 64; ++i)
      if (w[i] > 1u) m = 1;   // int32 words of 0/1 bools are <=1; packed uint8 are not
    smode = m; snseg = 0; *mode_p = m;
  }
  if (tid < K_MAX + 2) hist[tid] = 0;
  __syncthreads();
  int mode = smode;
  for (int t = tid; t < T_STEPS; t += 1024) {
    if (t != 0 && !start_flag(start, mode, t)) continue;
    int len = 1;
    while (t + len < T_STEPS && !start_flag(start, mode, t + len)) ++len;
    int slot = atomicAdd(&snseg, 1);
    if (slot < HCAP) {
      st0[slot] = t; slen[slot] = len;
      atomicAdd(&hist[min(len, K_MAX + 1)], 1);
    }
  }
  __syncthreads();
  if (tid == 0) {
    *nseg_p = min(snseg, HCAP);
    int acc = 0;
    for (int b = K_MAX + 1; b >= 1; --b) { off[b] = acc; acc += hist[b]; }
    for (int i = 0; i <= K_MAX; ++i) {
      int c = 0;
      for (int b = i + 1; b <= K_MAX + 1; ++b) c += hist[b];
      counts[i] = c;
    }
  }
  __syncthreads();
  int n = min(snseg, HCAP);
  for (int s = tid; s < n; s += 1024) {
    int pos = atomicAdd(&off[min(slen[s], K_MAX + 1)], 1);
    t0s[pos] = st0[s]; len_s[pos] = slen[s];
  }
}

// ---- all f32->bf16 conversions in one kernel (5 jobs by index range) ----
__global__ __launch_bounds__(256) void cvt_all(
    const float* __restrict__ x, const float* __restrict__ wpre,
    const float* __restrict__ wih, const float* __restrict__ w1,
    const float* __restrict__ w2,
    unsigned short* __restrict__ ox, unsigned short* __restrict__ owpre,
    unsigned short* __restrict__ owih, unsigned short* __restrict__ ow1,
    unsigned short* __restrict__ ow2) {
  int stride = gridDim.x * blockDim.x;
  for (int jq = blockIdx.x * blockDim.x + threadIdx.x; jq < 1900544; jq += stride) {
    const float* in; unsigned short* out; int o;
    if (jq < 524288)       { in = x;    out = ox;    o = jq; }
    else if (jq < 589824)  { in = wpre; out = owpre; o = jq - 524288; }
    else if (jq < 1376256) { in = wih;  out = owih;  o = jq - 589824; }
    else if (jq < 1638400) { in = w1;   out = ow1;   o = jq - 1376256; }
    else                   { in = w2;   out = ow2;   o = jq - 1638400; }
    float4 v = ((const float4*)in)[o];
    ushort4 r;
    r.x = f2b(v.x); r.y = f2b(v.y); r.z = f2b(v.z); r.w = f2b(v.w);
    ((ushort4*)out)[o] = r;
  }
}

// ---- fused: w_hh row r -> w_perm bf16 (row 3u+g) AND hg0[r] = dot(w_hh[r], state0).
// One pass over the 24 MB f32 w_hh instead of two (was cvt_whh_perm + matvec0).
__global__ __launch_bounds__(256) void whh_perm_mv(
    const float* __restrict__ in, const float* __restrict__ state0,
    unsigned short* __restrict__ out, float* __restrict__ hg0) {
  int r = blockIdx.x;                 // original row
  int g = r >> 10, u = r & 1023;
  unsigned short* dst = out + (size_t)(u * 3 + g) * D_REC;
  const float* src = in + (size_t)r * D_REC;
  int c = threadIdx.x * 4;            // 256 threads x 4 cols = 1024
  float4 v = *(const float4*)&src[c];
  ushort4 o; o.x = f2b(v.x); o.y = f2b(v.y); o.z = f2b(v.z); o.w = f2b(v.w);
  *(ushort4*)&dst[c] = o;
  float4 h4 = *(const float4*)&state0[c];
  float s = v.x * h4.x + v.y * h4.y + v.z * h4.z + v.w * h4.w;
#pragma unroll
  for (int off = 1; off < 64; off <<= 1) s += __shfl_xor(s, off);
  __shared__ float red[4];
  if ((threadIdx.x & 63) == 0) red[threadIdx.x >> 6] = s;
  __syncthreads();
  if (threadIdx.x == 0) hg0[r] = red[0] + red[1] + red[2] + red[3];
}

// C[M,N] = act(A[M,K] @ B[N,K]^T + bias[N]); bf16 in/out, f32 accum.
// dbuf global_load_lds staging + swizzled LDS (conflict-free, r7-proven).
// No XCD swizzle (r12 A/B: it trebled FETCH_SIZE — natural dispatch order wins).
template <int ACT, int MT, int NT>
__global__ __launch_bounds__(256) void gemm_tn(
    const unsigned short* __restrict__ A,
    const unsigned short* __restrict__ B,
    const float* __restrict__ bias,
    unsigned short* __restrict__ C,
    int M, int N, int K) {
  constexpr int BM = MT * 32, BN = NT * 32;
  constexpr int CA = BM / 64, CB = BN / 64;
  __shared__ unsigned short lds_a[2][BM * 32];
  __shared__ unsigned short lds_b[2][BN * 32];
  const int tid = threadIdx.x;
  const int lane = tid & 63;
  const int wave = tid >> 6;
  const int wr = wave >> 1, wc = wave & 1;
  const int row0 = blockIdx.x * BM, col0 = blockIdx.y * BN;
  f32x4_t acc[MT][NT] = {};
  const int lrow = lane & 15, j = lane >> 4;
  const unsigned short* srcA[CA];
  const unsigned short* srcB[CB];
#pragma unroll
  for (int p = 0; p < CA; ++p) {
    int slot = p * 256 + tid;
    srcA[p] = &A[(size_t)(row0 + (slot >> 2)) * K + swz_src_j(slot) * 8];
  }
#pragma unroll
  for (int p = 0; p < CB; ++p) {
    int slot = p * 256 + tid;
    srcB[p] = &B[(size_t)(col0 + (slot >> 2)) * K + swz_src_j(slot) * 8];
  }
  const int so = wave * 512;
  auto stage = [&](int buf, int k0) {
#pragma unroll
    for (int p = 0; p < CA; ++p)
      gload_lds16(srcA[p] + k0, &lds_a[buf][p * 2048 + so]);
#pragma unroll
    for (int p = 0; p < CB; ++p)
      gload_lds16(srcB[p] + k0, &lds_b[buf][p * 2048 + so]);
  };
  int aoff[MT], boff[NT];
#pragma unroll
  for (int m = 0; m < MT; ++m)
    aoff[m] = swz_read_off(wr * (MT * 16) + m * 16 + lrow, j);
#pragma unroll
  for (int n = 0; n < NT; ++n)
    boff[n] = swz_read_off(wc * (NT * 16) + n * 16 + lrow, j);
  const int nk = K >> 5;
  stage(0, 0);
  __syncthreads();
  int cur = 0;
  for (int t = 0; t < nk; ++t) {
    if (t + 1 < nk) stage(cur ^ 1, (t + 1) << 5);
    bf16x8_t af[MT], bfr[NT];
#pragma unroll
    for (int m = 0; m < MT; ++m)
      af[m] = *(const bf16x8_t*)&lds_a[cur][aoff[m]];
#pragma unroll
    for (int n = 0; n < NT; ++n)
      bfr[n] = *(const bf16x8_t*)&lds_b[cur][boff[n]];
#pragma unroll
    for (int m = 0; m < MT; ++m)
#pragma unroll
      for (int n = 0; n < NT; ++n)
        acc[m][n] = __builtin_amdgcn_mfma_f32_16x16x32_bf16(af[m], bfr[n], acc[m][n], 0, 0, 0);
    __syncthreads();
    cur ^= 1;
  }
#pragma unroll
  for (int n = 0; n < NT; ++n) {
    int col = col0 + wc * (NT * 16) + n * 16 + lrow;
    float bv = bias[col];
#pragma unroll
    for (int m = 0; m < MT; ++m) {
#pragma unroll
      for (int jj = 0; jj < 4; ++jj) {
        int row = row0 + wr * (MT * 16) + m * 16 + j * 4 + jj;
        float v = acc[m][n][jj] + bv;
        if (ACT) v = mishf(v);
        C[(size_t)row * N + col] = f2b(v);
      }
    }
  }
}

// ---- iteration 0 gate ----
__global__ __launch_bounds__(256) void gru_gate0(
    unsigned short* __restrict__ states, const unsigned short* __restrict__ igates,
    const void* __restrict__ start, const int* __restrict__ mode_p,
    const int* __restrict__ t0s, const int* __restrict__ nseg_p,
    const float* __restrict__ hg0, const float* __restrict__ state0,
    const float* __restrict__ b_n, float* __restrict__ Hf32,
    float* __restrict__ finals) {
  int p = blockIdx.x;
  if (p >= *nseg_p) return;
  int t0 = t0s[p];
  int mode = *mode_p;
  bool use_s0 = (t0 == 0) && !start_flag(start, mode, 0);
  size_t ib = (size_t)t0 * G3REC;
  for (int u = threadIdx.x; u < D_REC; u += 256) {
    float hp = use_s0 ? state0[u] : 0.f;
    float hr = use_s0 ? hg0[u] : 0.f;
    float hz = use_s0 ? hg0[D_REC + u] : 0.f;
    float hn = use_s0 ? hg0[2 * D_REC + u] : 0.f;
    float r = sigmf(b2f(igates[ib + u]) + hr);
    float z = sigmf(b2f(igates[ib + D_REC + u]) + hz);
    float n = tanhf(b2f(igates[ib + 2 * D_REC + u]) + r * (hn + b_n[u]));
    float hnew = n + z * (hp - n);
    Hf32[(size_t)p * D_REC + u] = hnew;
    states[(size_t)t0 * D_REC + u] = f2b(hnew);
    if (t0 == T_STEPS - 1) finals[u] = hnew;
  }
}

// ---- fused wavefront iteration i>=1: 64 segs x 96 w_perm rows (32 units).
// r10-proven: 25KB LDS, ~6 blocks/CU. Per-step weight re-read is amortized by
// BLOCK parallelism (r13 lesson: serializing steps into one block = 200us/step).
__global__ __launch_bounds__(256) void gru_iter(
    unsigned short* __restrict__ states,
    const unsigned short* __restrict__ igates,
    const unsigned short* __restrict__ w_perm,
    const int* __restrict__ t0s, const int* __restrict__ counts,
    const float* __restrict__ b_n, float* __restrict__ Hf32,
    float* __restrict__ finals, int iter) {
  const int count = counts[iter];
  const int row0 = blockIdx.x * 64;
  if (row0 >= count) return;
  const int u0 = blockIdx.y * 32;
  const int col0 = u0 * 3;
  __shared__ __align__(16) float smem_f[64 * 98];   // 25088 B
  unsigned short* sb = (unsigned short*)smem_f;
  float* hgl = smem_f;                              // [64][98] f32 after K-loop
  const int tid = threadIdx.x;
  const int lane = tid & 63, wave = tid >> 6;
  const int lrow = lane & 15, j = lane >> 4;
  const int rA = tid >> 2;
  const int c8sw = swz_src_j(tid) * 8;
  int gA = (row0 + rA < count) ? (t0s[row0 + rA] + iter - 1) : (t0s[0] + iter - 1);
  const unsigned short* srcA  = states + (size_t)gA * D_REC + c8sw;
  const unsigned short* srcB0 = w_perm + (size_t)(col0 + rA) * D_REC + c8sw;
  const unsigned short* srcB1 = w_perm + (size_t)(col0 + 64 + rA) * D_REC + c8sw; // tid<128
  const int soA = wave * 512;
  auto stage = [&](int buf, int k0) {
    gload_lds16(srcA + k0, sb + buf * 2048 + soA);
    gload_lds16(srcB0 + k0, sb + 4096 + buf * 3072 + soA);
    if (tid < 128)
      gload_lds16(srcB1 + k0, sb + 4096 + buf * 3072 + 2048 + soA);
  };
  f32x4_t acc[6] = {};
  const int aoff = swz_read_off(wave * 16 + lrow, j);
  int boff[6];
#pragma unroll
  for (int n = 0; n < 6; ++n)
    boff[n] = swz_read_off(n * 16 + lrow, j);
  stage(0, 0);
  __syncthreads();
  int cur = 0;
  for (int t = 0; t < 32; ++t) {
    if (t + 1 < 32) stage(cur ^ 1, (t + 1) << 5);
    const unsigned short* ca = sb + cur * 2048;
    const unsigned short* cb = sb + 4096 + cur * 3072;
    bf16x8_t af = *(const bf16x8_t*)&ca[aoff];
    bf16x8_t bfr[6];
#pragma unroll
    for (int n = 0; n < 6; ++n)
      bfr[n] = *(const bf16x8_t*)&cb[boff[n]];
#pragma unroll
    for (int n = 0; n < 6; ++n)
      acc[n] = __builtin_amdgcn_mfma_f32_16x16x32_bf16(af, bfr[n], acc[n], 0, 0, 0);
    __syncthreads();
    cur ^= 1;
  }
#pragma unroll
  for (int n = 0; n < 6; ++n)
#pragma unroll
    for (int jj = 0; jj < 4; ++jj) {
      int row = wave * 16 + j * 4 + jj;
      hgl[row * 98 + n * 16 + lrow] = acc[n][jj];
    }
  __syncthreads();
#pragma unroll
  for (int k = 0; k < 8; ++k) {
    int idx = k * 256 + tid;
    int pl = idx >> 5, ul = idx & 31;
    int p = row0 + pl;
    if (p >= count) continue;
    int t = t0s[p] + iter;
    int u = u0 + ul;
    float hr = hgl[pl * 98 + 3 * ul + 0];
    float hz = hgl[pl * 98 + 3 * ul + 1];
    float hn = hgl[pl * 98 + 3 * ul + 2];
    size_t ib = (size_t)t * G3REC;
    float hp = Hf32[(size_t)p * D_REC + u];
    float r = sigmf(b2f(igates[ib + u]) + hr);
    float z = sigmf(b2f(igates[ib + D_REC + u]) + hz);
    float n = tanhf(b2f(igates[ib + 2 * D_REC + u]) + r * (hn + b_n[u]));
    float hnew = n + z * (hp - n);
    Hf32[(size_t)p * D_REC + u] = hnew;
    states[(size_t)t * D_REC + u] = f2b(hnew);
    if (t == T_STEPS - 1) finals[u] = hnew;
  }
}

// ---- sequential cleanup for segments with len > K_MAX (counts[16]=0 for this input) ----
__global__ __launch_bounds__(256) void gru_cleanup(
    unsigned short* __restrict__ states, const unsigned short* __restrict__ igates,
    const unsigned short* __restrict__ w_perm,
    const int* __restrict__ t0s, const int* __restrict__ len_s,
    const int* __restrict__ counts, const float* __restrict__ b_n,
    const float* __restrict__ Hf32, float* __restrict__ finals) {
  int p = blockIdx.x;
  if (p >= counts[K_MAX]) return;
  int t0 = t0s[p], len = len_s[p];
  __shared__ float h[D_REC];
  __shared__ float hgl[G3REC];
  const int tid = threadIdx.x;
  for (int u = tid; u < D_REC; u += 256) h[u] = Hf32[(size_t)p * D_REC + u];
  __syncthreads();
  const int g = tid >> 4, l16 = tid & 15;
  for (int s = K_MAX; s < len; ++s) {
    int t = t0 + s;
    float hreg[64];
#pragma unroll
    for (int i = 0; i < 8; ++i) {
      float4 a = *(const float4*)&h[l16 * 8 + i * 128];
      float4 b = *(const float4*)&h[l16 * 8 + i * 128 + 4];
      hreg[i * 8 + 0] = a.x; hreg[i * 8 + 1] = a.y; hreg[i * 8 + 2] = a.z; hreg[i * 8 + 3] = a.w;
      hreg[i * 8 + 4] = b.x; hreg[i * 8 + 5] = b.y; hreg[i * 8 + 6] = b.z; hreg[i * 8 + 7] = b.w;
    }
    for (int row = g; row < G3REC; row += 16) {
      const unsigned short* wrow = w_perm + (size_t)row * D_REC;
      float sum = 0.f;
#pragma unroll
      for (int i = 0; i < 8; ++i) {
        bf16x8_t wv = *(const bf16x8_t*)&wrow[l16 * 8 + i * 128];
#pragma unroll
        for (int jj = 0; jj < 8; ++jj)
          sum += b2f((unsigned short)wv[jj]) * hreg[i * 8 + jj];
      }
#pragma unroll
      for (int o = 1; o < 16; o <<= 1) sum += __shfl_xor(sum, o);
      if (l16 == 0) hgl[row] = sum;
    }
    __syncthreads();
    size_t ib = (size_t)t * G3REC;
    for (int u = tid; u < D_REC; u += 256) {
      float r = sigmf(b2f(igates[ib + u]) + hgl[3 * u + 0]);
      float z = sigmf(b2f(igates[ib + D_REC + u]) + hgl[3 * u + 1]);
      float n = tanhf(b2f(igates[ib + 2 * D_REC + u]) + r * (hgl[3 * u + 2] + b_n[u]));
      float hnew = n + z * (h[u] - n);
      h[u] = hnew;
      states[(size_t)t * D_REC + u] = f2b(hnew);
      if (t == T_STEPS - 1) finals[u] = hnew;
    }
    __syncthreads();
  }
}

// ---- heads + dueling epilogue: one wave per 4 rows (weight loads amortized 4x) ----
__global__ __launch_bounds__(64) void heads_kernel(
    const unsigned short* __restrict__ y,
    const float* __restrict__ Wv, const float* __restrict__ bv,
    const float* __restrict__ Wa, const float* __restrict__ ba,
    const float* __restrict__ Ws, const float* __restrict__ bs,
    float* __restrict__ q) {
  const int t0 = blockIdx.x * 4, lane = threadIdx.x;
  float yv[4][16];
#pragma unroll
  for (int s = 0; s < 4; ++s) {
    const unsigned short* yr = y + (size_t)(t0 + s) * D_MLP;
#pragma unroll
    for (int c = 0; c < 2; ++c) {
      bf16x8_t v = *(const bf16x8_t*)&yr[lane * 16 + c * 8];
#pragma unroll
      for (int jj = 0; jj < 8; ++jj) yv[s][c * 8 + jj] = b2f((unsigned short)v[jj]);
    }
  }
  float mine[4] = {};
  for (int o = 0; o < 18; ++o) {
    const float* w = (o < 16) ? (Wa + (size_t)o * D_MLP) : (o == 16 ? Wv : Ws);
    float4 wv[4];
#pragma unroll
    for (int c = 0; c < 4; ++c) wv[c] = *(const float4*)&w[lane * 16 + c * 4];
#pragma unroll
    for (int s = 0; s < 4; ++s) {
      float ss = 0.f;
#pragma unroll
      for (int c = 0; c < 4; ++c)
        ss += wv[c].x * yv[s][c * 4 + 0] + wv[c].y * yv[s][c * 4 + 1] +
              wv[c].z * yv[s][c * 4 + 2] + wv[c].w * yv[s][c * 4 + 3];
#pragma unroll
      for (int off = 1; off < 64; off <<= 1) ss += __shfl_xor(ss, off);
      if (lane == o) mine[s] = ss;
    }
  }
#pragma unroll
  for (int s = 0; s < 4; ++s) {
    float m = mine[s];
    if (lane < 16) m += ba[lane];
    else if (lane == 16) m += bv[0];
    else if (lane == 17) m += bs[0];
    float a = (lane < 16) ? m : 0.f;
    float ss = a * a;
#pragma unroll
    for (int off = 1; off < 64; off <<= 1) ss += __shfl_xor(ss, off);
    float an = a / (1e-6f + sqrtf(ss));
    float ms = (lane < 16) ? an : 0.f;
#pragma unroll
    for (int off = 1; off < 64; off <<= 1) ms += __shfl_xor(ms, off);
    float adv = an - ms * (1.f / 16.f);
    float val = __shfl(m, 16);
    float sc = __shfl(m, 17);
    if (lane < 16) q[(size_t)(t0 + s) * D_ACT + lane] = val + sc * adv;
  }
}

extern "C" void kernel_launch(void* const* d_in, const int* in_sizes, int n_in,
                              void* d_out, int out_size, void* d_ws, size_t ws_size,
                              hipStream_t stream) {
  const float* x      = (const float*)d_in[0];
  const float* state0 = (const float*)d_in[1];
  const void*  start  = d_in[2];
  const float* W_pre  = (const float*)d_in[3];
  const float* b_pre  = (const float*)d_in[4];
  const float* w_ih   = (const float*)d_in[5];
  const float* w_hh   = (const float*)d_in[6];
  const float* b_ih   = (const float*)d_in[7];
  const float* b_n    = (const float*)d_in[8];
  const float* W1     = (const float*)d_in[9];
  const float* b1     = (const float*)d_in[10];
  const float* W2     = (const float*)d_in[11];
  const float* b2     = (const float*)d_in[12];
  const float* Wv     = (const float*)d_in[13];
  const float* bv     = (const float*)d_in[14];
  const float* Wa     = (const float*)d_in[15];
  const float* ba     = (const float*)d_in[16];
  const float* Ws     = (const float*)d_in[17];
  const float* bs     = (const float*)d_in[18];

  char* ws = (char*)d_ws;
  const size_t MB = 1ull << 20;
  unsigned short* igates = (unsigned short*)(ws);
  unsigned short* y2     = igates;
  unsigned short* xp     = (unsigned short*)(ws + 48 * MB);
  float*          Hf32   = (float*)(ws + 48 * MB);
  unsigned short* y1     = xp;
  unsigned short* states = (unsigned short*)(ws + 66 * MB);
  unsigned short* x_bf   = (unsigned short*)(ws + 82 * MB);
  unsigned short* w_perm = (unsigned short*)(ws + 82 * MB);
  unsigned short* Wpre_bf= (unsigned short*)(ws + 88 * MB);
  unsigned short* wih_bf = (unsigned short*)(ws + 88 * MB + 512 * 1024);
  unsigned short* W1_bf  = (unsigned short*)(ws + 94 * MB + 512 * 1024);
  unsigned short* W2_bf  = (unsigned short*)(ws + 96 * MB + 512 * 1024);
  char* seg = ws + 98 * MB + 512 * 1024;
  int* t0s     = (int*)(seg);
  int* len_s   = (int*)(seg + 32768);
  int* counts  = (int*)(seg + 65536);
  int* nseg_p  = (int*)(seg + 65536 + 128);
  int* mode_p  = (int*)(seg + 65536 + 192);
  float* hg0   = (float*)(seg + 65536 + 512);
  float* qout   = (float*)d_out;
  float* finals = qout + (size_t)T_STEPS * D_ACT;

  seg_all<<<1, 1024, 0, stream>>>(start, mode_p, nseg_p, t0s, len_s, counts);
  cvt_all<<<2048, 256, 0, stream>>>(x, W_pre, w_ih, W1, W2,
                                    x_bf, Wpre_bf, wih_bf, W1_bf, W2_bf);

  gemm_tn<1, 2, 2><<<dim3(128, 16), 256, 0, stream>>>(x_bf, Wpre_bf, b_pre, xp, T_STEPS, D_MLP, D_OBS);
  whh_perm_mv<<<3072, 256, 0, stream>>>(w_hh, state0, w_perm, hg0);
  gemm_tn<0, 4, 4><<<dim3(64, 24), 256, 0, stream>>>(xp, wih_bf, b_ih, igates, T_STEPS, G3REC, D_MLP);

  gru_gate0<<<HCAP, 256, 0, stream>>>(states, igates, start, mode_p, t0s, nseg_p,
                                      hg0, state0, b_n, Hf32, finals);
  for (int i = 1; i < K_MAX; ++i) {
    int mt = (8192 / (i + 1) + 63) / 64;  // count_i <= 8192/(i+1)
    gru_iter<<<dim3(mt, 32), 256, 0, stream>>>(states, igates, w_perm, t0s, counts,
                                               b_n, Hf32, finals, i);
  }
  gru_cleanup<<<512, 256, 0, stream>>>(states, igates, w_perm, t0s, len_s, counts,
                                       b_n, Hf32, finals);

  gemm_tn<1, 2, 2><<<dim3(128, 16), 256, 0, stream>>>(states, W1_bf, b1, y1, T_STEPS, D_MLP, D_REC);
  gemm_tn<1, 2, 2><<<dim3(128, 16), 256, 0, stream>>>(y1, W2_bf, b2, y2, T_STEPS, D_MLP, D_MLP);
  heads_kernel<<<2048, 64, 0, stream>>>(y2, Wv, bv, Wa, ba, Ws, bs, qout);
}